// Round 10
// baseline (802.568 us; speedup 1.0000x reference)
//
#include <hip/hip_runtime.h>

#define MAX_ITER 8192
#define NCHUNK   64
#define NCHUNKS  128          // MAX_ITER / NCHUNK
#define NSCAN    64           // scanner blocks, 1 sample each
#define NTHREADS 256

typedef unsigned long long u64;
#define KEY_MAX  0xffffffffffffffffull
#define POISON64 0xAAAAAAAAAAAAAAAAull   // d_ws re-poison pattern (0xAA bytes)

// IEEE fp32 ops, contraction off -> bitwise numpy match (verified many rounds).
__device__ __forceinline__ float mul_rn(float a, float b) {
#pragma clang fp contract(off)
  return a * b;
}
__device__ __forceinline__ float add_rn(float a, float b) {
#pragma clang fp contract(off)
  return a + b;
}
__device__ __forceinline__ float sub_rn(float a, float b) {
#pragma clang fp contract(off)
  return a - b;
}
__device__ __forceinline__ float dist2_rn(float px, float py, float sx, float sy) {
  const float dx = sub_rn(px, sx), dy = sub_rn(py, sy);
  return add_rn(mul_rn(dx, dx), mul_rn(dy, dy));
}
__device__ __forceinline__ float bcastf(float v, int lane) {
  return __int_as_float(__builtin_amdgcn_readlane(__float_as_int(v), lane));
}
__device__ __forceinline__ void st_agent(u64* p, u64 v) {
  __hip_atomic_store(p, v, __ATOMIC_RELAXED, __HIP_MEMORY_SCOPE_AGENT);
}
__device__ __forceinline__ u64 ld_agent(u64* p) {
  return __hip_atomic_load(p, __ATOMIC_RELAXED, __HIP_MEMORY_SCOPE_AGENT);
}
__device__ __forceinline__ u64 packf2(float x, float y) {
  return ((u64)__float_as_uint(y) << 32) | (u64)__float_as_uint(x);
}
__device__ __forceinline__ float lo32f(u64 v) {
  return __uint_as_float((unsigned)(v & 0xffffffffu));
}
__device__ __forceinline__ float hi32f(u64 v) {
  return __uint_as_float((unsigned)(v >> 32));
}
__device__ __forceinline__ void compiler_fence() {
  asm volatile("" ::: "memory");
}
// Exact (d2, idx) lex key: d2>=0 -> bit-monotone; ties -> lowest idx.
// idx bits 0..12 (max 8064); tag bits 13..20 (values 131..255; the 0xAA
// poison pattern decodes to tag 85 -> can never false-match).
__device__ __forceinline__ u64 mkkey(float d2, int idx) {
  return ((u64)__float_as_uint(d2) << 32) | (u64)(unsigned)idx;
}
__device__ __forceinline__ unsigned tagof(u64 kv) {
  return ((unsigned)(kv >> 13)) & 0xFFu;
}
__device__ __forceinline__ void load_sample(const float* __restrict__ u,
                                            const float* __restrict__ r,
                                            float gx, float gy, int idx,
                                            float& ox, float& oy) {
  const float uu = u[idx];
  if (uu < 0.1f) { ox = gx; oy = gy; }
  else { ox = mul_rn(r[2 * idx], 200.0f); oy = mul_rn(r[2 * idx + 1], 200.0f); }
}

__global__ __launch_bounds__(NTHREADS) void rrt_kernel(
    const float* __restrict__ state, const float* __restrict__ goal,
    const float* __restrict__ u, const float* __restrict__ r,
    float* __restrict__ out, unsigned* __restrict__ ws) {
  // scanners: staged node copy (bulk prescan source).
  // coordinator: its OWN self-copy (M-index -> coords via ds_read).
  __shared__ __align__(16) float2 nodesL[8064];
  __shared__ u64 sharedK[4];

  u64* outU  = (u64*)out;               // node i at outU[i] (float2-packed)
  // MbufK: 4-slot ring of 64 tagged keys.  Scanner iter i writes slot i&3,
  // tag i+131: M over [0..64(i+1)] computed vs chunk (i+3)'s sample.
  // Coordinator merge j (>=3) reads slot (j-3)&3 requiring tag == j+128
  // EXACTLY (tags are sample-specific -- r3 lesson).  Slot reuse (scanner
  // iter i+4) is gated on Nb chunk i+4, published only AFTER merge j=i+3
  // consumed iter i's M; future tags cannot appear before consumption.
  u64* MbufK = (u64*)(ws + 64);         // bytes 256..2303
  u64* Nb    = (u64*)(ws + 576);        // bytes 2304..67839
  // Nb[m] = node m+1, written ONCE; 0xAA poison is an impossible node value
  // (all nodes >= 0; 0xAAAAAAAA is negative).  Data IS the ready flag ->
  // no nflag, no vmcnt drain, no init guard.  u64 stores don't tear.

  const int tid  = threadIdx.x;
  const int wave = tid >> 6;
  const int lane = tid & 63;
  const int blk  = blockIdx.x;

  const float n0x = state[0], n0y = state[1];
  const float gx = goal[0],  gy = goal[1];

  if (blk == 0) {
    // ================= coordinator: one wave, no barriers ==================
    if (tid == 0) st_agent(&outU[0], packf2(n0x, n0y));   // node 0
    if (tid >= 64) return;

    // samples: s = chunk j, s1 = chunk j+1 (s2 prefetched in-loop)
    float sx, sy, s1x, s1y;
    load_sample(u, r, gx, gy, lane, sx, sy);
    load_sample(u, r, gx, gy, NCHUNK + lane, s1x, s1y);
    // 2-deep carries.  Invariant at merge j: c1 = min over chunks j-2, j-1
    // vs s_j (chunk j-2 folded while c2, chunk j-1 while c1 -> ascending
    // index order; strict < -> lowest idx on ties).  c2 = chunk j-1 vs s_{j+1}.
    float c1d = 3.0e38f, c1x = 0.0f, c1y = 0.0f;
    float c2d = 3.0e38f, c2x = 0.0f, c2y = 0.0f;
    u64 kvPre = 0;

    for (int j = 0; j < NCHUNKS; ++j) {
      const int c = j * NCHUNK;

      // prefetch chunk j+2 sample (becomes s1 next iter)
      float s2x = 0.0f, s2y = 0.0f;
      if (j + 2 < NCHUNKS)
        load_sample(u, r, gx, gy, (j + 2) * NCHUNK + lane, s2x, s2y);

      // ---- merge argmin over [0..64j]:
      //   M (j>=3): [0..64(j-2)] incl node0; M wins ties (lower indices)
      //   c1: chunks j-2..j-1... (disjoint higher range, strict <)
      float bd2, bx, by;
      if (j >= 3) {
        const unsigned want = (unsigned)(j + 128);
        u64 kv = kvPre;   // issued at end of chunk j-1; target published >=1
        if (!__all((int)(tagof(kv) == want))) {        // chunk-period earlier
          u64* slot = MbufK + (((unsigned)(j - 3)) & 3u) * 64;
          for (;;) {
            kv = ld_agent(&slot[lane]);
            if (__all((int)(tagof(kv) == want))) break;
            __builtin_amdgcn_s_sleep(1);
          }
        }
        compiler_fence();
        bd2 = hi32f(kv);
        const unsigned midx = (unsigned)kv & 0x1FFFu;
        if (midx == 0u) { bx = n0x; by = n0y; }
        else { const float2 p = nodesL[midx - 1]; bx = p.x; by = p.y; }
      } else {
        bd2 = dist2_rn(n0x, n0y, sx, sy);
        bx = n0x; by = n0y;
      }
      if (c1d < bd2) { bd2 = c1d; bx = c1x; by = c1y; }

      // carry shift (AFTER merge)
      c1d = c2d; c1x = c2x; c1y = c2y;
      c2d = 3.0e38f; c2x = 0.0f; c2y = 0.0f;

      // pre-steer (verified math)
      float dirx = sub_rn(sx, bx), diry = sub_rn(sy, by);
      float dist = __fsqrt_rn(add_rn(bd2, 1e-12f));
      float scl = (dist > 5.0f) ? __fdiv_rn(5.0f, dist) : 1.0f;
      float nx = add_rn(bx, mul_rn(dirx, scl));
      float ny = add_rn(by, mul_rn(diry, scl));

      // ---- scan + candidate pops: EXACT sequential semantics (r9-proven).
      // Scan bits cover every event whose q_t is unchanged (bd2 only
      // decreases); q-changed steps are re-added via ballot(upd) at the pop
      // that changed them.  Pops ascend; each step pops <= once; pop-time
      // recompute gives bit-exact sequential behavior.
      u64 cand;
      {
        unsigned candLo = 0u, candHi = 0u;
        #pragma unroll
        for (int t = 0; t < NCHUNK; ++t) {
          const float px = bcastf(nx, t);
          const float py = bcastf(ny, t);
          const float d = dist2_rn(px, py, sx, sy);
          const u64 bal = __ballot(d < bd2);
          const u64 hi = (t < 63) ? (bal >> (t + 1)) : 0ull;   // lanes > t
          if (t < 32) candLo |= (hi != 0ull) ? (1u << t) : 0u;
          else        candHi |= (hi != 0ull) ? (1u << (t - 32)) : 0u;
        }
        cand = ((u64)candHi << 32) | (u64)candLo;
      }
      while (cand) {
        const int t = (int)__builtin_ctzll(cand);
        cand &= (cand - 1);
        const float px = bcastf(nx, t);
        const float py = bcastf(ny, t);
        const float d = dist2_rn(px, py, sx, sy);
        const bool upd = (lane > t) && (d < bd2);
        const u64 ub = __ballot(upd);
        if (ub != 0ull) {
          if (upd) {            // exact sequential update body
            bd2 = d; bx = px; by = py;
            dirx = sub_rn(sx, bx); diry = sub_rn(sy, by);
            dist = __fsqrt_rn(add_rn(d, 1e-12f));
            scl = (dist > 5.0f) ? __fdiv_rn(5.0f, dist) : 1.0f;
            nx = add_rn(bx, mul_rn(dirx, scl));
            ny = add_rn(by, mul_rn(diry, scl));
          }
          cand |= ub;           // updated lanes' steps become candidates (>t)
        }
      }

      // publish: LDS self-copy + output + poison-gated broadcast.  No drain.
      if (c + lane < 8064) {
        float2 p; p.x = nx; p.y = ny;
        nodesL[c + lane] = p;             // node c+lane+1 at LDS idx c+lane
      }
      const u64 pv = packf2(nx, ny);
      st_agent(&outU[c + lane + 1], pv);
      st_agent(&Nb[c + lane], pv);
      // speculative ring load for merge j+1 (slot (j-2)&3): in flight over
      // the carry fold below; target published >=1 period ago -> expect hit.
      if (j >= 2 && j + 1 < NCHUNKS) {
        u64* ns = MbufK + (((unsigned)(j - 2)) & 3u) * 64;
        kvPre = ld_agent(&ns[lane]);
      }

      // ---- combined carry fold (chunk j's nodes vs s_{j+1} -> c1 and
      // s_{j+2} -> c2): off the serial path, hides in the kvPre shadow.
      // Ascending t, strict < -> exact ties.  (c2 vs garbage s2 at j=126 is
      // never consumed: merge 128 doesn't exist.)
      if (j + 1 < NCHUNKS) {
        #pragma unroll 8
        for (int t = 0; t < NCHUNK; ++t) {
          const float px = bcastf(nx, t);
          const float py = bcastf(ny, t);
          const float d1 = dist2_rn(px, py, s1x, s1y);
          if (d1 < c1d) { c1d = d1; c1x = px; c1y = py; }
          const float d2 = dist2_rn(px, py, s2x, s2y);
          if (d2 < c2d) { c2d = d2; c2x = px; c2y = py; }
        }
      }

      sx = s1x; sy = s1y; s1x = s2x; s1y = s2y;
    }
  } else {
    // ================= scanners: blocks 1..64, one sample each =============
    // iter i (0..124): issue Nb load for chunk i; bulk-scan [1..64i] from LDS
    // (staged by prior iters) + node 0 under it; wave-0 tail validates the
    // fresh chunk-i nodes via the poison gate (arrival IS the signal), folds
    // one per lane, publishes tag i+131 into ring slot i&3 (for merge j=i+3,
    // vs chunk (i+3)'s sample).  ~2 chunk-periods of slack before use.
    const int b = blk - 1;

    for (int i = 0; i < NCHUNKS - 3; ++i) {
      const int c = i * NCHUNK;

      u64 nv = POISON64;
      if (wave == 0) nv = ld_agent(&Nb[c + lane]);   // issue early, check late

      // my sample: chunk i+3, slot b
      float sx, sy;
      load_sample(u, r, gx, gy, (i + 3) * NCHUNK + b, sx, sy);

      // ---- bulk scan of staged nodes [1..64i] + node 0 ----
      u64 key = KEY_MAX;
      if (tid == 0) key = mkkey(dist2_rn(n0x, n0y, sx, sy), 0);
      // 256 lanes stride node pairs; float4 = nodes (jj, jj+1), jj odd
      for (int jj = 1 + 2 * tid; jj < c; jj += 2 * NTHREADS) {
        const float4 p = *(const float4*)&nodesL[jj - 1];
        const u64 ka = mkkey(dist2_rn(p.x, p.y, sx, sy), jj);
        const u64 kb = mkkey(dist2_rn(p.z, p.w, sx, sy), jj + 1);
        if (ka < key) key = ka;     // lower idx first: exact argmin ties
        if (kb < key) key = kb;
      }
      #pragma unroll
      for (int m = 32; m >= 1; m >>= 1) {
        const u64 ok = __shfl_xor(key, m, 64);
        if (ok < key) key = ok;
      }
      if (lane == 0) sharedK[wave] = key;
      __syncthreads();                  // barrier A: partials ready

      // ---- wave-0 tail: validate fresh chunk i, stage, fold, publish ----
      if (wave == 0) {
        u64 kk = (lane < 4) ? sharedK[lane] : KEY_MAX;
        u64 ok = __shfl_xor(kk, 1, 64); if (ok < kk) kk = ok;
        ok = __shfl_xor(kk, 2, 64);     if (ok < kk) kk = ok;

        while (!__all((int)(nv != POISON64))) {   // data arrival = signal
          __builtin_amdgcn_s_sleep(1);
          nv = ld_agent(&Nb[c + lane]);
        }
        compiler_fence();
        const float px = lo32f(nv), py = hi32f(nv);
        {
          float2 p; p.x = px; p.y = py;
          nodesL[c + lane] = p;           // stage chunk i for future bulks
          const u64 ki = mkkey(dist2_rn(px, py, sx, sy), c + lane + 1);
          if (ki < kk) kk = ki;           // (d2,idx) key: order-free ties
        }
        #pragma unroll
        for (int m = 32; m >= 1; m >>= 1) {
          const u64 o2 = __shfl_xor(kk, m, 64);
          if (o2 < kk) kk = o2;
        }
        if (lane == 0) {
          u64* slot = MbufK + (((unsigned)i) & 3u) * 64;
          st_agent(&slot[b], kk | ((u64)(unsigned)(i + 131) << 13));
        }
      }
      // barrier B: gates next iter's bulk reads of freshly staged nodes and
      // sharedK reuse.
      __syncthreads();
    }
  }
}

extern "C" void kernel_launch(void* const* d_in, const int* in_sizes, int n_in,
                              void* d_out, int out_size, void* d_ws, size_t ws_size,
                              hipStream_t stream) {
  const float* state = (const float*)d_in[0];
  const float* goal  = (const float*)d_in[1];
  const float* u     = (const float*)d_in[2];
  const float* r     = (const float*)d_in[3];
  float* out = (float*)d_out;
  unsigned* ws = (unsigned*)d_ws;
  (void)in_sizes; (void)n_in; (void)out_size; (void)ws_size;
  rrt_kernel<<<NSCAN + 1, NTHREADS, 0, stream>>>(state, goal, u, r, out, ws);
}

// Round 11
// 386.028 us; speedup vs baseline: 2.0790x; 2.0790x over previous
//
#include <hip/hip_runtime.h>

#define MAX_ITER 8192
#define NCHUNK   64
#define NCHUNKS  128          // MAX_ITER / NCHUNK
#define NSCAN    64           // scanner blocks, 1 sample each
#define NTHREADS 256

typedef unsigned long long u64;
#define KEY_MAX  0xffffffffffffffffull
#define POISON64 0xAAAAAAAAAAAAAAAAull   // d_ws re-poison pattern (0xAA bytes)

// IEEE fp32 ops, contraction off -> bitwise numpy match (verified many rounds).
__device__ __forceinline__ float mul_rn(float a, float b) {
#pragma clang fp contract(off)
  return a * b;
}
__device__ __forceinline__ float add_rn(float a, float b) {
#pragma clang fp contract(off)
  return a + b;
}
__device__ __forceinline__ float sub_rn(float a, float b) {
#pragma clang fp contract(off)
  return a - b;
}
__device__ __forceinline__ float dist2_rn(float px, float py, float sx, float sy) {
  const float dx = sub_rn(px, sx), dy = sub_rn(py, sy);
  return add_rn(mul_rn(dx, dx), mul_rn(dy, dy));
}
__device__ __forceinline__ float bcastf(float v, int lane) {
  return __int_as_float(__builtin_amdgcn_readlane(__float_as_int(v), lane));
}
__device__ __forceinline__ void st_agent(u64* p, u64 v) {
  __hip_atomic_store(p, v, __ATOMIC_RELAXED, __HIP_MEMORY_SCOPE_AGENT);
}
__device__ __forceinline__ u64 ld_agent(u64* p) {
  return __hip_atomic_load(p, __ATOMIC_RELAXED, __HIP_MEMORY_SCOPE_AGENT);
}
__device__ __forceinline__ u64 packf2(float x, float y) {
  return ((u64)__float_as_uint(y) << 32) | (u64)__float_as_uint(x);
}
__device__ __forceinline__ float lo32f(u64 v) {
  return __uint_as_float((unsigned)(v & 0xffffffffu));
}
__device__ __forceinline__ float hi32f(u64 v) {
  return __uint_as_float((unsigned)(v >> 32));
}
__device__ __forceinline__ void compiler_fence() {
  asm volatile("" ::: "memory");
}
// Exact (d2, idx) lex key: d2>=0 -> bit-monotone; ties -> lowest idx.
// Scanner-published keys also carry a tag in bits 13..20 (131..255); the
// coordinator STRIPS the tag before key comparison.  0xAA poison -> tag 85,
// can never false-match.
__device__ __forceinline__ u64 mkkey(float d2, int idx) {
  return ((u64)__float_as_uint(d2) << 32) | (u64)(unsigned)idx;
}
__device__ __forceinline__ unsigned tagof(u64 kv) {
  return ((unsigned)(kv >> 13)) & 0xFFu;
}
__device__ __forceinline__ void load_sample(const float* __restrict__ u,
                                            const float* __restrict__ r,
                                            float gx, float gy, int idx,
                                            float& ox, float& oy) {
  const float uu = u[idx];
  if (uu < 0.1f) { ox = gx; oy = gy; }
  else { ox = mul_rn(r[2 * idx], 200.0f); oy = mul_rn(r[2 * idx + 1], 200.0f); }
}

__global__ __launch_bounds__(NTHREADS) void rrt_kernel(
    const float* __restrict__ state, const float* __restrict__ goal,
    const float* __restrict__ u, const float* __restrict__ r,
    float* __restrict__ out, unsigned* __restrict__ ws) {
  // LDS union: scanner blocks stage nodes; block 0 uses a small scratch for
  // the 4-wave coordinator team.  Different blocks -> no aliasing.
  __shared__ __align__(16) union {
    struct { float2 nodes[7936]; u64 K[4]; } s;                    // 63520 B
    struct { u64 qtmp[64]; float bd2[64]; u64 mask[4];
             u64 fk1[4][64]; u64 fk2[4][64]; } c;                  //  4896 B
  } sh;

  u64* outU  = (u64*)out;               // node i at outU[i] (float2-packed)
  // MbufK: 4-slot ring of 64 tagged keys (lag-3, r10-verified).  Scanner
  // iter i writes slot i&3, tag i+131: M over [0..64(i+1)] vs chunk (i+3)'s
  // sample.  Coordinator merge j (>=3) reads slot (j-3)&3, tag == j+128
  // EXACTLY.  Slot reuse (iter i+4) gated on Nb chunk i+4, published only
  // after merge j=i+3 consumed iter i's M.
  u64* MbufK = (u64*)(ws + 64);         // bytes 256..2303
  u64* Nb    = (u64*)(ws + 576);        // bytes 2304..67839
  // Nb[m] = node m+1, written ONCE; 0xAA poison is an impossible node value
  // (all nodes >= 0; 0xAAAAAAAA is negative).  Data IS the ready flag ->
  // no nflag, no vmcnt drain, no init guard.  u64 stores don't tear.

  const int tid  = threadIdx.x;
  const int wave = tid >> 6;
  const int lane = tid & 63;
  const int blk  = blockIdx.x;

  const float n0x = state[0], n0y = state[1];
  const float gx = goal[0],  gy = goal[1];

  if (blk == 0) {
    // ============ coordinator team: 4 waves, 4 barriers per chunk ==========
    if (tid == 0) st_agent(&outU[0], packf2(n0x, n0y));   // node 0

    // ALL waves maintain the rolling samples (identical loads -> identical
    // values): s = chunk j, s1 = chunk j+1.
    float sx, sy, s1x, s1y;
    load_sample(u, r, gx, gy, lane, sx, sy);
    load_sample(u, r, gx, gy, NCHUNK + lane, s1x, s1y);
    // wave-0 carry keys.  Invariant at merge j: c1K = min-key over chunks
    // j-2, j-1 vs s_j; c2K = chunk j-1 vs s_{j+1}.  (d2,idx) keys: order-
    // free exact ties.
    u64 c1K = KEY_MAX, c2K = KEY_MAX;
    u64 kvPre = 0, wvM = 0, wvC1 = 0;
    bool preOK = false;

    for (int j = 0; j < NCHUNKS; ++j) {
      const int c = j * NCHUNK;

      // all waves: prefetch chunk j+2 sample (becomes s1 next iter)
      float s2x = 0.0f, s2y = 0.0f;
      if (j + 2 < NCHUNKS)
        load_sample(u, r, gx, gy, (j + 2) * NCHUNK + lane, s2x, s2y);

      float bd2 = 0.0f, bx = 0.0f, by = 0.0f, nx = 0.0f, ny = 0.0f;

      // ---- Phase A (wave 0): merge + steer + share ----
      if (wave == 0) {
        u64 Mkey; float mx = n0x, my = n0y;
        if (j >= 3) {
          const unsigned want = (unsigned)(j + 128);
          u64 kv;
          if (preOK) {
            kv = kvPre;                 // gather wvM already in flight
          } else {                      // rare fallback: poll + dep. gather
            u64* slot = MbufK + (((unsigned)(j - 3)) & 3u) * 64;
            for (;;) {
              kv = ld_agent(&slot[lane]);
              if (__all((int)(tagof(kv) == want))) break;
              __builtin_amdgcn_s_sleep(1);
            }
            compiler_fence();
            const unsigned im = (unsigned)kv & 0x1FFFu;
            wvM = ld_agent(&Nb[(im ? im : 1u) - 1u]);
          }
          const unsigned midx = (unsigned)kv & 0x1FFFu;
          Mkey = (kv & 0xFFFFFFFF00000000ull) | (u64)midx;   // strip tag
          if (midx) { mx = lo32f(wvM); my = hi32f(wvM); }
        } else {
          Mkey = mkkey(dist2_rn(n0x, n0y, sx, sy), 0);
        }
        // merge: index ranges disjoint (M idx <= 64(j-2) < carry idx) ->
        // plain u64 key-min is the exact lex argmin incl. tie-breaks.
        const float cx = lo32f(wvC1), cy = hi32f(wvC1);   // c1K winner coords
        const bool cWin = (c1K < Mkey);
        const u64 win = cWin ? c1K : Mkey;
        bd2 = hi32f(win);
        bx = cWin ? cx : mx;
        by = cWin ? cy : my;
        // pre-steer (verified math)
        const float dirx = sub_rn(sx, bx), diry = sub_rn(sy, by);
        const float dist = __fsqrt_rn(add_rn(bd2, 1e-12f));
        const float scl = (dist > 5.0f) ? __fdiv_rn(5.0f, dist) : 1.0f;
        nx = add_rn(bx, mul_rn(dirx, scl));
        ny = add_rn(by, mul_rn(diry, scl));
        sh.c.qtmp[lane] = packf2(nx, ny);   // pre-pop q
        sh.c.bd2[lane] = bd2;               // post-merge bd2
      }
      __syncthreads();                      // B1: (q, bd2) shared

      // ---- Phase B (all waves): scan t-range [16w, 16w+16) ----
      // Exactness as r9: bits computed from pre-pop q and post-merge bd2;
      // pops recheck exactly and re-add changed steps.
      {
        float qxl, qyl, bb;
        if (wave == 0) { qxl = nx; qyl = ny; bb = bd2; }
        else {
          const u64 qv = sh.c.qtmp[lane];
          qxl = lo32f(qv); qyl = hi32f(qv);
          bb = sh.c.bd2[lane];
        }
        unsigned m16 = 0;
        const int t0 = wave * 16;
        #pragma unroll
        for (int tt = 0; tt < 16; ++tt) {
          const int t = t0 + tt;
          const float px = bcastf(qxl, t);
          const float py = bcastf(qyl, t);
          const float d = dist2_rn(px, py, sx, sy);
          const u64 bal = __ballot(d < bb);
          if (t < 63 && (bal >> (t + 1)) != 0ull) m16 |= (1u << tt);
        }
        sh.c.mask[wave] = ((u64)m16) << (wave * 16);
      }
      __syncthreads();                      // B2: masks ready

      // ---- Phase C (wave 0): pops (r9-exact) + publish ----
      if (wave == 0) {
        u64 cand = sh.c.mask[0] | sh.c.mask[1] | sh.c.mask[2] | sh.c.mask[3];
        // speculative ring load for merge j+1 (slot (j-2)&3): issue BEFORE
        // pops for maximal flight time; decoded in phase E.
        if (j >= 2 && j + 1 < NCHUNKS)
          kvPre = ld_agent(&MbufK[(((unsigned)(j - 2)) & 3u) * 64 + lane]);
        while (cand) {
          const int t = (int)__builtin_ctzll(cand);
          cand &= (cand - 1);
          const float px = bcastf(nx, t);
          const float py = bcastf(ny, t);
          const float d = dist2_rn(px, py, sx, sy);
          const bool upd = (lane > t) && (d < bd2);
          const u64 ub = __ballot(upd);
          if (ub != 0ull) {
            if (upd) {                  // exact sequential update body
              bd2 = d; bx = px; by = py;
              const float dirx = sub_rn(sx, bx), diry = sub_rn(sy, by);
              const float dist = __fsqrt_rn(add_rn(d, 1e-12f));
              const float scl = (dist > 5.0f) ? __fdiv_rn(5.0f, dist) : 1.0f;
              nx = add_rn(bx, mul_rn(dirx, scl));
              ny = add_rn(by, mul_rn(diry, scl));
            }
            cand |= ub;                 // changed steps become candidates
          }
        }
        const u64 pv = packf2(nx, ny);
        st_agent(&outU[c + lane + 1], pv);
        st_agent(&Nb[c + lane], pv);
        sh.c.qtmp[lane] = pv;           // FINAL q for the folds
      }
      __syncthreads();                      // B3: final q ready

      // ---- Phase D (all waves): fold t-range vs s_{j+1} and s_{j+2} ----
      {
        float qfx, qfy;
        { const u64 qv = sh.c.qtmp[lane]; qfx = lo32f(qv); qfy = hi32f(qv); }
        u64 k1 = KEY_MAX, k2 = KEY_MAX;
        const int t0 = wave * 16;
        #pragma unroll
        for (int tt = 0; tt < 16; ++tt) {
          const int t = t0 + tt;
          const float px = bcastf(qfx, t);
          const float py = bcastf(qfy, t);
          const int idx = c + t + 1;
          const u64 kk1 = mkkey(dist2_rn(px, py, s1x, s1y), idx);
          if (kk1 < k1) k1 = kk1;
          const u64 kk2 = mkkey(dist2_rn(px, py, s2x, s2y), idx);
          if (kk2 < k2) k2 = kk2;
        }
        sh.c.fk1[wave][lane] = k1;
        sh.c.fk2[wave][lane] = k2;
      }
      __syncthreads();                      // B4: fold partials ready

      // ---- Phase E (wave 0): combine partials + pre-issue next gathers ----
      if (wave == 0) {
        u64 f1 = sh.c.fk1[0][lane];
        { u64 x = sh.c.fk1[1][lane]; if (x < f1) f1 = x;
          x = sh.c.fk1[2][lane]; if (x < f1) f1 = x;
          x = sh.c.fk1[3][lane]; if (x < f1) f1 = x; }
        u64 f2 = sh.c.fk2[0][lane];
        { u64 x = sh.c.fk2[1][lane]; if (x < f2) f2 = x;
          x = sh.c.fk2[2][lane]; if (x < f2) f2 = x;
          x = sh.c.fk2[3][lane]; if (x < f2) f2 = x; }
        c1K = (c2K < f1) ? c2K : f1;    // key-min: exact, order-free ties
        c2K = f2;                       // (garbage s2 folds never consumed)
        // pre-issue winner-coord gathers for NEXT merge (hidden ~1 phase):
        const unsigned ic = (unsigned)(c1K & 0x1FFFu);
        wvC1 = ld_agent(&Nb[(ic ? ic : 1u) - 1u]);
        preOK = false;
        if (j >= 2 && j + 1 < NCHUNKS) {
          preOK = __all((int)(tagof(kvPre) == (unsigned)(j + 129)));
          if (preOK) {
            const unsigned im = (unsigned)kvPre & 0x1FFFu;
            wvM = ld_agent(&Nb[(im ? im : 1u) - 1u]);
          }
        }
      }

      // all waves: rotate samples
      sx = s1x; sy = s1y; s1x = s2x; s1y = s2y;
    }
  } else {
    // ================= scanners: blocks 1..64, one sample each =============
    // (r10 verbatim, union-renamed)  iter i (0..124): issue Nb load for
    // chunk i; bulk-scan [1..64i] from LDS + node 0 under it; wave-0 tail
    // validates fresh chunk i via the poison gate, folds one per lane,
    // publishes tag i+131 into ring slot i&3 (for merge j=i+3).
    const int b = blk - 1;

    for (int i = 0; i < NCHUNKS - 3; ++i) {
      const int c = i * NCHUNK;

      u64 nv = POISON64;
      if (wave == 0) nv = ld_agent(&Nb[c + lane]);   // issue early, check late

      // my sample: chunk i+3, slot b
      float sx, sy;
      load_sample(u, r, gx, gy, (i + 3) * NCHUNK + b, sx, sy);

      // ---- bulk scan of staged nodes [1..64i] + node 0 ----
      u64 key = KEY_MAX;
      if (tid == 0) key = mkkey(dist2_rn(n0x, n0y, sx, sy), 0);
      // 256 lanes stride node pairs; float4 = nodes (jj, jj+1), jj odd
      for (int jj = 1 + 2 * tid; jj < c; jj += 2 * NTHREADS) {
        const float4 p = *(const float4*)&sh.s.nodes[jj - 1];
        const u64 ka = mkkey(dist2_rn(p.x, p.y, sx, sy), jj);
        const u64 kb = mkkey(dist2_rn(p.z, p.w, sx, sy), jj + 1);
        if (ka < key) key = ka;     // lower idx first: exact argmin ties
        if (kb < key) key = kb;
      }
      #pragma unroll
      for (int m = 32; m >= 1; m >>= 1) {
        const u64 ok = __shfl_xor(key, m, 64);
        if (ok < key) key = ok;
      }
      if (lane == 0) sh.s.K[wave] = key;
      __syncthreads();                  // barrier A: partials ready

      // ---- wave-0 tail: validate fresh chunk i, stage, fold, publish ----
      if (wave == 0) {
        u64 kk = (lane < 4) ? sh.s.K[lane] : KEY_MAX;
        u64 ok = __shfl_xor(kk, 1, 64); if (ok < kk) kk = ok;
        ok = __shfl_xor(kk, 2, 64);     if (ok < kk) kk = ok;

        while (!__all((int)(nv != POISON64))) {   // data arrival = signal
          __builtin_amdgcn_s_sleep(1);
          nv = ld_agent(&Nb[c + lane]);
        }
        compiler_fence();
        const float px = lo32f(nv), py = hi32f(nv);
        {
          float2 p; p.x = px; p.y = py;
          sh.s.nodes[c + lane] = p;       // stage chunk i for future bulks
          const u64 ki = mkkey(dist2_rn(px, py, sx, sy), c + lane + 1);
          if (ki < kk) kk = ki;           // (d2,idx) key: order-free ties
        }
        #pragma unroll
        for (int m = 32; m >= 1; m >>= 1) {
          const u64 o2 = __shfl_xor(kk, m, 64);
          if (o2 < kk) kk = o2;
        }
        if (lane == 0) {
          u64* slot = MbufK + (((unsigned)i) & 3u) * 64;
          st_agent(&slot[b], kk | ((u64)(unsigned)(i + 131) << 13));
        }
      }
      // barrier B: gates next iter's bulk reads of freshly staged nodes and
      // K reuse.
      __syncthreads();
    }
  }
}

extern "C" void kernel_launch(void* const* d_in, const int* in_sizes, int n_in,
                              void* d_out, int out_size, void* d_ws, size_t ws_size,
                              hipStream_t stream) {
  const float* state = (const float*)d_in[0];
  const float* goal  = (const float*)d_in[1];
  const float* u     = (const float*)d_in[2];
  const float* r     = (const float*)d_in[3];
  float* out = (float*)d_out;
  unsigned* ws = (unsigned*)d_ws;
  (void)in_sizes; (void)n_in; (void)out_size; (void)ws_size;
  rrt_kernel<<<NSCAN + 1, NTHREADS, 0, stream>>>(state, goal, u, r, out, ws);
}

// Round 12
// 366.446 us; speedup vs baseline: 2.1901x; 1.0534x over previous
//
#include <hip/hip_runtime.h>

#define MAX_ITER 8192
#define NCHUNK   64
#define NCHUNKS  128          // MAX_ITER / NCHUNK
#define NSCAN    64           // scanner blocks, 1 sample each
#define NTHREADS 512
#define NWAVES   8
#define TPW      8            // t's per wave in scan/fold phases

typedef unsigned long long u64;
#define KEY_MAX  0xffffffffffffffffull
#define POISON64 0xAAAAAAAAAAAAAAAAull   // d_ws re-poison pattern (0xAA bytes)

// IEEE fp32 ops, contraction off -> bitwise numpy match (verified many rounds).
__device__ __forceinline__ float mul_rn(float a, float b) {
#pragma clang fp contract(off)
  return a * b;
}
__device__ __forceinline__ float add_rn(float a, float b) {
#pragma clang fp contract(off)
  return a + b;
}
__device__ __forceinline__ float sub_rn(float a, float b) {
#pragma clang fp contract(off)
  return a - b;
}
__device__ __forceinline__ float dist2_rn(float px, float py, float sx, float sy) {
  const float dx = sub_rn(px, sx), dy = sub_rn(py, sy);
  return add_rn(mul_rn(dx, dx), mul_rn(dy, dy));
}
__device__ __forceinline__ float bcastf(float v, int lane) {
  return __int_as_float(__builtin_amdgcn_readlane(__float_as_int(v), lane));
}
__device__ __forceinline__ void st_agent(u64* p, u64 v) {
  __hip_atomic_store(p, v, __ATOMIC_RELAXED, __HIP_MEMORY_SCOPE_AGENT);
}
__device__ __forceinline__ u64 ld_agent(u64* p) {
  return __hip_atomic_load(p, __ATOMIC_RELAXED, __HIP_MEMORY_SCOPE_AGENT);
}
__device__ __forceinline__ u64 packf2(float x, float y) {
  return ((u64)__float_as_uint(y) << 32) | (u64)__float_as_uint(x);
}
__device__ __forceinline__ float lo32f(u64 v) {
  return __uint_as_float((unsigned)(v & 0xffffffffu));
}
__device__ __forceinline__ float hi32f(u64 v) {
  return __uint_as_float((unsigned)(v >> 32));
}
__device__ __forceinline__ void compiler_fence() {
  asm volatile("" ::: "memory");
}
// Exact (d2, idx) lex key: d2>=0 -> bit-monotone; ties -> lowest idx.
// Scanner-published keys also carry a tag in bits 13..20 (131..255); the
// coordinator STRIPS the tag before key comparison.  0xAA poison -> tag 85,
// can never false-match.
__device__ __forceinline__ u64 mkkey(float d2, int idx) {
  return ((u64)__float_as_uint(d2) << 32) | (u64)(unsigned)idx;
}
__device__ __forceinline__ unsigned tagof(u64 kv) {
  return ((unsigned)(kv >> 13)) & 0xFFu;
}
__device__ __forceinline__ void load_sample(const float* __restrict__ u,
                                            const float* __restrict__ r,
                                            float gx, float gy, int idx,
                                            float& ox, float& oy) {
  const float uu = u[idx];
  if (uu < 0.1f) { ox = gx; oy = gy; }
  else { ox = mul_rn(r[2 * idx], 200.0f); oy = mul_rn(r[2 * idx + 1], 200.0f); }
}

__global__ __launch_bounds__(NTHREADS) void rrt_kernel(
    const float* __restrict__ state, const float* __restrict__ goal,
    const float* __restrict__ u, const float* __restrict__ r,
    float* __restrict__ out, unsigned* __restrict__ ws) {
  // LDS union: scanner blocks stage nodes; block 0 uses a small scratch for
  // the 8-wave coordinator team.  Different blocks -> no aliasing.
  __shared__ __align__(16) union {
    struct { float2 nodes[7936]; u64 K[NWAVES]; } s;               // 63552 B
    struct { u64 qtmp[64]; float bd2[64]; u64 mask[NWAVES];
             u64 fk1[NWAVES][64]; u64 fk2[NWAVES][64]; } c;        //  9024 B
  } sh;

  u64* outU  = (u64*)out;               // node i at outU[i] (float2-packed)
  // MbufK: 4-slot ring of 64 tagged keys (lag-3, r10/r11-verified).  Scanner
  // iter i writes slot i&3, tag i+131: M over [0..64(i+1)] vs chunk (i+3)'s
  // sample.  Coordinator merge j (>=3) reads slot (j-3)&3, tag == j+128
  // EXACTLY.  Slot reuse (iter i+4) gated on Nb chunk i+4, published only
  // after merge j=i+3 consumed iter i's M.
  u64* MbufK = (u64*)(ws + 64);         // bytes 256..2303
  u64* Nb    = (u64*)(ws + 576);        // bytes 2304..67839
  // Nb[m] = node m+1, written ONCE; 0xAA poison is an impossible node value
  // (all nodes >= 0; 0xAAAAAAAA is negative).  Data IS the ready flag ->
  // no nflag, no vmcnt drain, no init guard.  u64 stores don't tear.

  const int tid  = threadIdx.x;
  const int wave = tid >> 6;
  const int lane = tid & 63;
  const int blk  = blockIdx.x;

  const float n0x = state[0], n0y = state[1];
  const float gx = goal[0],  gy = goal[1];

  if (blk == 0) {
    // ============ coordinator team: 8 waves, 4 barriers per chunk ==========
    if (tid == 0) st_agent(&outU[0], packf2(n0x, n0y));   // node 0

    // ALL waves maintain the rolling samples (identical loads -> identical
    // values): s = chunk j, s1 = chunk j+1.
    float sx, sy, s1x, s1y;
    load_sample(u, r, gx, gy, lane, sx, sy);
    load_sample(u, r, gx, gy, NCHUNK + lane, s1x, s1y);
    // wave-0 carry keys.  Invariant at merge j: c1K = min-key over chunks
    // j-2, j-1 vs s_j; c2K = chunk j-1 vs s_{j+1}.  (d2,idx) keys: order-
    // free exact ties.
    u64 c1K = KEY_MAX, c2K = KEY_MAX;
    u64 kvPre = 0, wvM = 0, wvC1 = 0;
    bool preOK = false;

    for (int j = 0; j < NCHUNKS; ++j) {
      const int c = j * NCHUNK;

      // all waves: prefetch chunk j+2 sample (becomes s1 next iter)
      float s2x = 0.0f, s2y = 0.0f;
      if (j + 2 < NCHUNKS)
        load_sample(u, r, gx, gy, (j + 2) * NCHUNK + lane, s2x, s2y);

      float bd2 = 0.0f, bx = 0.0f, by = 0.0f, nx = 0.0f, ny = 0.0f;

      // ---- Phase A (wave 0): merge + steer + share ----
      if (wave == 0) {
        u64 Mkey; float mx = n0x, my = n0y;
        if (j >= 3) {
          const unsigned want = (unsigned)(j + 128);
          u64 kv;
          if (preOK) {
            kv = kvPre;                 // gather wvM already in flight
          } else {                      // rare fallback: poll + dep. gather
            u64* slot = MbufK + (((unsigned)(j - 3)) & 3u) * 64;
            for (;;) {
              kv = ld_agent(&slot[lane]);
              if (__all((int)(tagof(kv) == want))) break;
              __builtin_amdgcn_s_sleep(1);
            }
            compiler_fence();
            const unsigned im = (unsigned)kv & 0x1FFFu;
            wvM = ld_agent(&Nb[(im ? im : 1u) - 1u]);
          }
          const unsigned midx = (unsigned)kv & 0x1FFFu;
          Mkey = (kv & 0xFFFFFFFF00000000ull) | (u64)midx;   // strip tag
          if (midx) { mx = lo32f(wvM); my = hi32f(wvM); }
        } else {
          Mkey = mkkey(dist2_rn(n0x, n0y, sx, sy), 0);
        }
        // merge: index ranges disjoint (M idx <= 64(j-2) < carry idx) ->
        // plain u64 key-min is the exact lex argmin incl. tie-breaks.
        const float cx = lo32f(wvC1), cy = hi32f(wvC1);   // c1K winner coords
        const bool cWin = (c1K < Mkey);
        const u64 win = cWin ? c1K : Mkey;
        bd2 = hi32f(win);
        bx = cWin ? cx : mx;
        by = cWin ? cy : my;
        // pre-steer (verified math)
        const float dirx = sub_rn(sx, bx), diry = sub_rn(sy, by);
        const float dist = __fsqrt_rn(add_rn(bd2, 1e-12f));
        const float scl = (dist > 5.0f) ? __fdiv_rn(5.0f, dist) : 1.0f;
        nx = add_rn(bx, mul_rn(dirx, scl));
        ny = add_rn(by, mul_rn(diry, scl));
        sh.c.qtmp[lane] = packf2(nx, ny);   // pre-pop q
        sh.c.bd2[lane] = bd2;               // post-merge bd2
      }
      __syncthreads();                      // B1: (q, bd2) shared

      // ---- Phase B (all waves): scan t-range [TPW*w, TPW*w+TPW) ----
      // Exactness as r9: bits computed from pre-pop q and post-merge bd2;
      // pops recheck exactly and re-add changed steps.
      {
        float qxl, qyl, bb;
        if (wave == 0) { qxl = nx; qyl = ny; bb = bd2; }
        else {
          const u64 qv = sh.c.qtmp[lane];
          qxl = lo32f(qv); qyl = hi32f(qv);
          bb = sh.c.bd2[lane];
        }
        unsigned mw = 0;
        const int t0 = wave * TPW;
        #pragma unroll
        for (int tt = 0; tt < TPW; ++tt) {
          const int t = t0 + tt;
          const float px = bcastf(qxl, t);
          const float py = bcastf(qyl, t);
          const float d = dist2_rn(px, py, sx, sy);
          const u64 bal = __ballot(d < bb);
          if (t < 63 && (bal >> (t + 1)) != 0ull) mw |= (1u << tt);
        }
        sh.c.mask[wave] = ((u64)mw) << (wave * TPW);
      }
      __syncthreads();                      // B2: masks ready

      // ---- Phase C (wave 0): pops (r9-exact) + publish ----
      if (wave == 0) {
        u64 cand = 0;
        #pragma unroll
        for (int w = 0; w < NWAVES; ++w) cand |= sh.c.mask[w];
        // speculative ring load for merge j+1 (slot (j-2)&3): issue BEFORE
        // pops for maximal flight time; decoded in phase E.
        if (j >= 2 && j + 1 < NCHUNKS)
          kvPre = ld_agent(&MbufK[(((unsigned)(j - 2)) & 3u) * 64 + lane]);
        while (cand) {
          const int t = (int)__builtin_ctzll(cand);
          cand &= (cand - 1);
          const float px = bcastf(nx, t);
          const float py = bcastf(ny, t);
          const float d = dist2_rn(px, py, sx, sy);
          const bool upd = (lane > t) && (d < bd2);
          const u64 ub = __ballot(upd);
          if (ub != 0ull) {
            if (upd) {                  // exact sequential update body
              bd2 = d; bx = px; by = py;
              const float dirx = sub_rn(sx, bx), diry = sub_rn(sy, by);
              const float dist = __fsqrt_rn(add_rn(d, 1e-12f));
              const float scl = (dist > 5.0f) ? __fdiv_rn(5.0f, dist) : 1.0f;
              nx = add_rn(bx, mul_rn(dirx, scl));
              ny = add_rn(by, mul_rn(diry, scl));
            }
            cand |= ub;                 // changed steps become candidates
          }
        }
        const u64 pv = packf2(nx, ny);
        st_agent(&outU[c + lane + 1], pv);
        st_agent(&Nb[c + lane], pv);
        sh.c.qtmp[lane] = pv;           // FINAL q for the folds
      }
      __syncthreads();                      // B3: final q ready

      // ---- Phase D (all waves): fold t-range vs s_{j+1} and s_{j+2} ----
      {
        float qfx, qfy;
        if (wave == 0) { qfx = nx; qfy = ny; }
        else { const u64 qv = sh.c.qtmp[lane]; qfx = lo32f(qv); qfy = hi32f(qv); }
        u64 k1 = KEY_MAX, k2 = KEY_MAX;
        const int t0 = wave * TPW;
        #pragma unroll
        for (int tt = 0; tt < TPW; ++tt) {
          const int t = t0 + tt;
          const float px = bcastf(qfx, t);
          const float py = bcastf(qfy, t);
          const int idx = c + t + 1;
          const u64 kk1 = mkkey(dist2_rn(px, py, s1x, s1y), idx);
          if (kk1 < k1) k1 = kk1;
          const u64 kk2 = mkkey(dist2_rn(px, py, s2x, s2y), idx);
          if (kk2 < k2) k2 = kk2;
        }
        sh.c.fk1[wave][lane] = k1;
        sh.c.fk2[wave][lane] = k2;
      }
      __syncthreads();                      // B4: fold partials ready

      // ---- Phase E (wave 0): combine partials + pre-issue next gathers ----
      if (wave == 0) {
        u64 f1 = sh.c.fk1[0][lane];
        u64 f2 = sh.c.fk2[0][lane];
        #pragma unroll
        for (int w = 1; w < NWAVES; ++w) {
          const u64 x1 = sh.c.fk1[w][lane]; if (x1 < f1) f1 = x1;
          const u64 x2 = sh.c.fk2[w][lane]; if (x2 < f2) f2 = x2;
        }
        c1K = (c2K < f1) ? c2K : f1;    // key-min: exact, order-free ties
        c2K = f2;                       // (garbage s2 folds never consumed)
        // pre-issue winner-coord gathers for NEXT merge (hidden ~1 phase):
        const unsigned ic = (unsigned)(c1K & 0x1FFFu);
        wvC1 = ld_agent(&Nb[(ic ? ic : 1u) - 1u]);
        preOK = false;
        if (j >= 2 && j + 1 < NCHUNKS) {
          preOK = __all((int)(tagof(kvPre) == (unsigned)(j + 129)));
          if (preOK) {
            const unsigned im = (unsigned)kvPre & 0x1FFFu;
            wvM = ld_agent(&Nb[(im ? im : 1u) - 1u]);
          }
        }
      }

      // all waves: rotate samples
      sx = s1x; sy = s1y; s1x = s2x; s1y = s2y;
    }
  } else {
    // ================= scanners: blocks 1..64, one sample each =============
    // (r10/r11 verbatim, 8 waves)  iter i (0..124): issue Nb load for
    // chunk i; bulk-scan [1..64i] from LDS + node 0 under it; wave-0 tail
    // validates fresh chunk i via the poison gate, folds one per lane,
    // publishes tag i+131 into ring slot i&3 (for merge j=i+3).
    const int b = blk - 1;

    for (int i = 0; i < NCHUNKS - 3; ++i) {
      const int c = i * NCHUNK;

      u64 nv = POISON64;
      if (wave == 0) nv = ld_agent(&Nb[c + lane]);   // issue early, check late

      // my sample: chunk i+3, slot b
      float sx, sy;
      load_sample(u, r, gx, gy, (i + 3) * NCHUNK + b, sx, sy);

      // ---- bulk scan of staged nodes [1..64i] + node 0 ----
      u64 key = KEY_MAX;
      if (tid == 0) key = mkkey(dist2_rn(n0x, n0y, sx, sy), 0);
      // 512 lanes stride node pairs; float4 = nodes (jj, jj+1), jj odd
      for (int jj = 1 + 2 * tid; jj < c; jj += 2 * NTHREADS) {
        const float4 p = *(const float4*)&sh.s.nodes[jj - 1];
        const u64 ka = mkkey(dist2_rn(p.x, p.y, sx, sy), jj);
        const u64 kb = mkkey(dist2_rn(p.z, p.w, sx, sy), jj + 1);
        if (ka < key) key = ka;     // lower idx first: exact argmin ties
        if (kb < key) key = kb;
      }
      #pragma unroll
      for (int m = 32; m >= 1; m >>= 1) {
        const u64 ok = __shfl_xor(key, m, 64);
        if (ok < key) key = ok;
      }
      if (lane == 0) sh.s.K[wave] = key;
      __syncthreads();                  // barrier A: partials ready

      // ---- wave-0 tail: validate fresh chunk i, stage, fold, publish ----
      if (wave == 0) {
        u64 kk = (lane < NWAVES) ? sh.s.K[lane] : KEY_MAX;
        u64 ok = __shfl_xor(kk, 1, 64); if (ok < kk) kk = ok;
        ok = __shfl_xor(kk, 2, 64);     if (ok < kk) kk = ok;
        ok = __shfl_xor(kk, 4, 64);     if (ok < kk) kk = ok;

        while (!__all((int)(nv != POISON64))) {   // data arrival = signal
          __builtin_amdgcn_s_sleep(1);
          nv = ld_agent(&Nb[c + lane]);
        }
        compiler_fence();
        const float px = lo32f(nv), py = hi32f(nv);
        {
          float2 p; p.x = px; p.y = py;
          sh.s.nodes[c + lane] = p;       // stage chunk i for future bulks
          const u64 ki = mkkey(dist2_rn(px, py, sx, sy), c + lane + 1);
          if (ki < kk) kk = ki;           // (d2,idx) key: order-free ties
        }
        #pragma unroll
        for (int m = 32; m >= 1; m >>= 1) {
          const u64 o2 = __shfl_xor(kk, m, 64);
          if (o2 < kk) kk = o2;
        }
        if (lane == 0) {
          u64* slot = MbufK + (((unsigned)i) & 3u) * 64;
          st_agent(&slot[b], kk | ((u64)(unsigned)(i + 131) << 13));
        }
      }
      // barrier B: gates next iter's bulk reads of freshly staged nodes and
      // K reuse.
      __syncthreads();
    }
  }
}

extern "C" void kernel_launch(void* const* d_in, const int* in_sizes, int n_in,
                              void* d_out, int out_size, void* d_ws, size_t ws_size,
                              hipStream_t stream) {
  const float* state = (const float*)d_in[0];
  const float* goal  = (const float*)d_in[1];
  const float* u     = (const float*)d_in[2];
  const float* r     = (const float*)d_in[3];
  float* out = (float*)d_out;
  unsigned* ws = (unsigned*)d_ws;
  (void)in_sizes; (void)n_in; (void)out_size; (void)ws_size;
  rrt_kernel<<<NSCAN + 1, NTHREADS, 0, stream>>>(state, goal, u, r, out, ws);
}